// Round 14
// baseline (13446.753 us; speedup 1.0000x reference)
//
#include <hip/hip_runtime.h>
#include <math.h>

// ---------------------------------------------------------------------------
// LSTMModel round 14: REMOVE the two stats barriers (fam0/fam2). Stats lines
// are self-validating: [word0]=cnt, [word2,3]=sum,sq. Publishers: data adds,
// vmcnt(0) drain, then cnt add (per-line release). Consumers poll cnt==16
// per line inside the aggregation loop (pipelined, no grid rendezvous).
// Only fam1/fam3 (h-ready) barriers remain; L0 backpressure folded into
// fam1 wait (polls fam3(t-6)). Everything else as R13: closer barriers with
// replicated flags, depth-8 h rotation, staggered acq fences, sc1 h stores.
// Blocks 0..127 = layer 0 (step t), 128..255 = layer 1 (one step behind).
// ---------------------------------------------------------------------------

#define N_   128
#define T_   256
#define QN_  16
#define INX  24
#define H_   1024
#define G4   4096
#define FDIM 768
#define EPS_ 1e-5f
#define K0_  1792
#define K1_  2048
#define NSLOT 8
#define HSZ  ((size_t)N_ * H_)
#define SSLOT 16
#define SLSZ (512 * 8 * 16)      // floats per stats slot: 512 entries x 8 banks x 16

typedef unsigned short u16;
typedef unsigned int u32;
typedef unsigned long long u64;
typedef __attribute__((ext_vector_type(8))) short bf16x8;
typedef __attribute__((ext_vector_type(4))) float f32x4;

__device__ __forceinline__ float sigmoidf_(float v) { return 1.0f / (1.0f + expf(-v)); }

__device__ __forceinline__ u16 f2bf(float f) {
  unsigned u = __float_as_uint(f);
  u += 0x7fffu + ((u >> 16) & 1u);
  return (u16)(u >> 16);
}
__device__ __forceinline__ float bf2f(u16 x) {
  return __uint_as_float((u32)x << 16);
}

__device__ __forceinline__ void st_u64g(void* p, u64 v) {
  __hip_atomic_store((u64*)p, v, __ATOMIC_RELAXED, __HIP_MEMORY_SCOPE_AGENT);
}
__device__ __forceinline__ void st_f32g(float* p, float v) {
  __hip_atomic_store(p, v, __ATOMIC_RELAXED, __HIP_MEMORY_SCOPE_AGENT);
}
__device__ __forceinline__ u64 ld_u64g(const void* p) {
  return __hip_atomic_load((const u64*)p, __ATOMIC_RELAXED, __HIP_MEMORY_SCOPE_AGENT);
}
__device__ __forceinline__ u32 ld_u32g(const u32* p) {
  return __hip_atomic_load(p, __ATOMIC_RELAXED, __HIP_MEMORY_SCOPE_AGENT);
}
__device__ __forceinline__ void atomAdd_(float* p, float v) {
  __hip_atomic_fetch_add(p, v, __ATOMIC_RELAXED, __HIP_MEMORY_SCOPE_AGENT);
}
__device__ __forceinline__ void atomAddU_(u32* p, u32 v) {
  __hip_atomic_fetch_add(p, v, __ATOMIC_RELAXED, __HIP_MEMORY_SCOPE_AGENT);
}

// ---- BatchNorm stats over the (N*T, 16) numeric block --------------------
__global__ __launch_bounds__(256) void bn_stats_k(const float* __restrict__ x,
    const float* __restrict__ gamma, const float* __restrict__ beta,
    float* __restrict__ scale, float* __restrict__ shift) {
  int q = blockIdx.x;
  int tid = threadIdx.x;
  float s = 0.f, s2 = 0.f;
  for (int r = tid; r < N_ * T_; r += 256) {
    float v = x[(size_t)r * INX + q];
    s += v; s2 += v * v;
  }
  for (int off = 32; off; off >>= 1) { s += __shfl_down(s, off); s2 += __shfl_down(s2, off); }
  __shared__ float red[2][4];
  int w = tid >> 6;
  if ((tid & 63) == 0) { red[0][w] = s; red[1][w] = s2; }
  __syncthreads();
  if (tid == 0) {
    float S = 0.f, S2 = 0.f;
    for (int i = 0; i < 4; ++i) { S += red[0][i]; S2 += red[1][i]; }
    float m   = S  / (float)(N_ * T_);
    float var = S2 / (float)(N_ * T_) - m * m;
    float rs  = rsqrtf(var + EPS_);
    scale[q] = rs * gamma[q];
    shift[q] = beta[q] - m * rs * gamma[q];
  }
}

// ---- Feature build for ALL steps: ft[t][n][768] bf16 ---------------------
__global__ __launch_bounds__(256) void feats_all_k(const float* __restrict__ x,
    const float* __restrict__ scale, const float* __restrict__ shift,
    const float* __restrict__ QnV, const float* __restrict__ QlV,
    u16* __restrict__ ft) {
  int rid = blockIdx.x;              // t*128 + n
  int t = rid >> 7, n = rid & 127;
  const float* xr = x + ((size_t)n * T_ + t) * INX;
  u16* frow = ft + (size_t)rid * FDIM;
  for (int f = threadIdx.x; f < FDIM; f += 256) {
    int d = f & 31;
    float v;
    if (f < 512) {
      int q = f >> 5;
      v = (xr[q] * scale[q] + shift[q]) * QnV[q * 32 + d];
    } else {
      int cg_ = (f - 512) >> 5;
      int idx = (int)xr[QN_ + cg_] + cg_ * 100;
      v = QlV[idx * 32 + d];
    }
    frow[f] = f2bf(v);
  }
}

// ---- Weight convert: W[k][col] fp32 -> WtP[(b*32+j)][k] bf16 --------------
__global__ __launch_bounds__(256) void wconv_k(const float* __restrict__ W,
                                               u16* __restrict__ WtP, int K) {
  __shared__ u16 L[64][72];
  int tid = threadIdx.x;
  int k0 = blockIdx.x * 64, n0 = blockIdx.y * 64;
#pragma unroll
  for (int it = 0; it < 16; ++it) {
    int e = it * 256 + tid;
    int r = e >> 6, c = e & 63;
    L[r][c] = f2bf(W[(size_t)(k0 + r) * G4 + n0 + c]);
  }
  __syncthreads();
  int n = tid >> 2, ks = (tid & 3) << 4;
  int col = n0 + n;
  int b = (col & 1023) >> 3;
  int j = (col >> 10) * 8 + (col & 7);
  u16* dst = WtP + ((size_t)(b * 32 + j)) * K + k0 + ks;
#pragma unroll
  for (int jj = 0; jj < 16; ++jj) dst[jj] = L[ks + jj][n];
}

// ---- closer barrier with replicated flags (h barriers only) --------------
#define SUBC(fam, sub)  cnts[((fam) * 8 + (sub)) * 16]
#define FLAGR(fam, rep) cnts[(32 + (fam) * 32 + (rep)) * 16]

__device__ __forceinline__ void arrive_(u32* cnts, int fam, int sub) {
  __hip_atomic_fetch_add(&SUBC(fam, sub), 1u,
                         __ATOMIC_RELAXED, __HIP_MEMORY_SCOPE_AGENT);
}
__device__ __forceinline__ void pollsub_(u32* cnts, int fam, int sub, u32 tgt16) {
  while (__hip_atomic_load(&SUBC(fam, sub), __ATOMIC_RELAXED, __HIP_MEMORY_SCOPE_AGENT) < tgt16)
    __builtin_amdgcn_s_sleep(1);
}
__device__ __forceinline__ void pollflag_(u32* cnts, int fam, int rep, u32 t1) {
  while (__hip_atomic_load(&FLAGR(fam, rep), __ATOMIC_RELAXED, __HIP_MEMORY_SCOPE_AGENT) < t1)
    __builtin_amdgcn_s_sleep(1);
}
__device__ __forceinline__ void acqf_(int tid) {
  if (tid < 64) __builtin_amdgcn_fence(__ATOMIC_ACQUIRE, "agent");  // buffer_inv only
  __syncthreads();
}

__device__ __forceinline__ void waitfam_(u32* cnts, int fam, u32 t1, int isCloser,
                                         int tid, int rep, int bpFam, u32 bpT1) {
  if (isCloser) { if (tid < 8) pollsub_(cnts, fam, tid, t1 * 16u); }
  else          { if (tid == 0) pollflag_(cnts, fam, rep, t1); }
  if (tid == 8 && bpFam >= 0) pollflag_(cnts, bpFam, rep, bpT1);
  __syncthreads();
  if (isCloser && tid < 32)
    __hip_atomic_store(&FLAGR(fam, tid), t1, __ATOMIC_RELAXED, __HIP_MEMORY_SCOPE_AGENT);
}

// ---- K-partial MFMA over NS slices of 32 (cached A loads) ----------------
template<int NS>
__device__ __forceinline__ void gpart(f32x4& a0, f32x4& a1,
    const u16* __restrict__ abase, const u16* __restrict__ wb0,
    const u16* __restrict__ wb1, int cb, int swz, int g) {
#pragma unroll 8
  for (int kc = 0; kc < NS; ++kc) {
    bf16x8 av = *(const bf16x8*)(abase + kc * 32);
    int c = ((cb + kc * 4 + g) ^ swz) << 3;
    bf16x8 bv0 = *(const bf16x8*)(wb0 + c);
    bf16x8 bv1 = *(const bf16x8*)(wb1 + c);
    a0 = __builtin_amdgcn_mfma_f32_16x16x32_bf16(av, bv0, a0, 0, 0, 0);
    a1 = __builtin_amdgcn_mfma_f32_16x16x32_bf16(av, bv1, a1, 0, 0, 0);
  }
}

__device__ __forceinline__ float lnrm2(float v, float2 sq, float g_, float b_) {
  float mean = sq.x * (1.f / (float)H_);
  float var  = sq.y * (1.f / (float)H_) - mean * mean;
  return (v - mean) * rsqrtf(var + EPS_) * g_ + b_;
}

// publish stats with per-line release counter; then (separately) aggregate
// with per-line cnt polling. Line layout: w0=cnt, w2=sum, w3=sq.
__device__ __forceinline__ void stats_publish(float* stA, const f32x4& accb0,
    const f32x4& accb1, int wbase, int g4, int ga, int hh, int bank) {
#pragma unroll
  for (int r = 0; r < 4; ++r) {
    int row = wbase + g4 * 4 + r;
    float s0 = accb0[r], q0 = s0 * s0, s1 = accb1[r], q1 = s1 * s1;
#pragma unroll
    for (int off = 1; off <= 4; off <<= 1) {
      s0 += __shfl_xor(s0, off); q0 += __shfl_xor(q0, off);
      s1 += __shfl_xor(s1, off); q1 += __shfl_xor(q1, off);
    }
    if (hh == 0) {
      float* l0 = &stA[(((row * 4 + ga) * 8) + bank) * 16];
      float* l1 = &stA[(((row * 4 + ga + 2) * 8) + bank) * 16];
      atomAdd_(l0 + 2, s0);  atomAdd_(l0 + 3, q0);
      atomAdd_(l1 + 2, s1);  atomAdd_(l1 + 3, q1);
    }
  }
  asm volatile("s_waitcnt vmcnt(0)" ::: "memory");   // data adds acked
#pragma unroll
  for (int r = 0; r < 4; ++r) {
    int row = wbase + g4 * 4 + r;
    if (hh == 0) {
      atomAddU_((u32*)&stA[(((row * 4 + ga) * 8) + bank) * 16], 1u);
      atomAddU_((u32*)&stA[(((row * 4 + ga + 2) * 8) + bank) * 16], 1u);
    }
  }
}

__device__ __forceinline__ float2 stats_gather(const float* stA, int tid) {
  const float* lp = stA + (size_t)tid * 128;   // entry tid, 8 banked lines
  float s = 0.f, q = 0.f;
#pragma unroll
  for (int k = 0; k < 8; ++k) {
    const u32* ln = (const u32*)(lp + k * 16);
    while (ld_u32g(ln) < 16u) __builtin_amdgcn_s_sleep(1);
    u64 v = ld_u64g(lp + k * 16 + 2);
    s += __uint_as_float((u32)v);
    q += __uint_as_float((u32)(v >> 32));
  }
  return make_float2(s, q);
}

// ---- The layer-pipelined persistent kernel --------------------------------
__global__ __launch_bounds__(512, 2) void persist_k(
    const u16* __restrict__ WtP0, const u16* __restrict__ WtP1,
    const u16* __restrict__ ft,
    u16* __restrict__ h0s, u16* __restrict__ h1s,
    const float* __restrict__ b0, const float* __restrict__ b1,
    const float* __restrict__ lng, const float* __restrict__ lnb,
    const float* __restrict__ fcW, const float* __restrict__ fcb,
    float* __restrict__ statsA, float* __restrict__ statsB,
    u32* __restrict__ cnts, float* __restrict__ out) {
  __shared__ u16 wlds[32 * K1_];               // 128 KiB (L0 uses 112 KiB)
  __shared__ float2 sstat[512];                // aggregated LN stats (4 KiB)
  const int bcu = blockIdx.x, tid = threadIdx.x;
  const int isL0 = bcu < 128;
  const int b    = isL0 ? bcu : bcu - 128;
  const int wave = tid >> 6, lane = tid & 63;
  const int vcol = lane & 15, g4 = lane >> 4;
  const int ga = vcol >> 3, hh = vcol & 7;
  const int swz = vcol & 7;
  const int rowA  = wave * 16 + vcol;
  const int wbase = wave * 16;
  const int sub   = b >> 4;
  const int bank  = b & 7;
  const int rep   = b & 31;
  const int fph   = b & 7;        // staggered fence phase
  const int hbase = b * 8;
  const int K = isL0 ? K0_ : K1_;

  // ---- one-time: weight slice global -> LDS (XOR chunk swizzle) ----
  {
    const u16* wsrc = isL0 ? WtP0 + (size_t)b * 32 * K0_
                           : WtP1 + (size_t)b * 32 * K1_;
    int kc8 = K >> 3;
    for (int cid = tid; cid < 32 * kc8; cid += 512) {
      int j = cid / kc8, ck = cid - j * kc8;
      *(bf16x8*)&wlds[j * K + ((ck ^ (j & 7)) << 3)] =
          *(const bf16x8*)&wsrc[(size_t)j * K + (ck << 3)];
    }
  }
  __syncthreads();
  acqf_(tid);   // clean any cross-replay stale lines once

  const u16* wb0p = &wlds[vcol * K];
  const u16* wb1p = &wlds[(vcol + 16) * K];

  const float* bW   = isL0 ? b0 : b1;
  const float* lngW = isL0 ? lng : lng + 4 * H_;
  const float* lnbW = isL0 ? lnb : lnb + 4 * H_;
  const int colA = ga * H_ + hbase + hh;
  const int colB = (ga + 2) * H_ + hbase + hh;
  const float bias0v = bW[colA], bias1v = bW[colB];
  const float lng0v = lngW[colA], lnb0v = lnbW[colA];
  const float lng1v = lngW[colB], lnb1v = lnbW[colB];
  const float fcb0 = fcb[0], fcb1 = fcb[1];

  float cst[4] = {0.f, 0.f, 0.f, 0.f};

  if (isL0) {
    // ================= LAYER 0 half ====================================
    f32x4 acN0 = {0.f, 0.f, 0.f, 0.f}, acN1 = acN0;
    gpart<24>(acN0, acN1, ft + (size_t)rowA * FDIM + g4 * 8, wb0p, wb1p, 128, swz, g4);

    for (int t = 0; t < T_; ++t) {
      const u32 t1 = (u32)(t + 1);
      u16* h0w = h0s + (size_t)(t & (NSLOT - 1)) * HSZ;
      const u16* h0r = h0s + (size_t)((t - 1) & (NSLOT - 1)) * HSZ;
      float* stA = statsA + (size_t)(t & (SSLOT - 1)) * SLSZ;

      // gemm0 h-part: cached reads of h0(t-1) slot (never-stale by rotation)
      f32x4 ac0 = acN0, ac1 = acN1;
      gpart<32>(ac0, ac1, h0r + (size_t)rowA * H_ + g4 * 8, wb0p, wb1p, 0, swz, g4);
      f32x4 accb0, accb1;
#pragma unroll
      for (int r = 0; r < 4; ++r) { accb0[r] = ac0[r] + bias0v; accb1[r] = ac1[r] + bias1v; }

      // stats publish with per-line release (NO barrier)
      stats_publish(stA, accb0, accb1, wbase, g4, ga, hh, bank);

      // slack: zero stats slot t+8 (own 32 lines, words 0..3), ft for t+1
      {
        float* zs = statsA + (size_t)((t + 8) & (SSLOT - 1)) * SLSZ;
        if (tid < 128) st_f32g(&zs[(b * 32 + (tid >> 2)) * 16 + (tid & 3)], 0.f);
        int tn = (t + 1 < T_) ? t + 1 : t;
        acN0[0] = 0.f; acN0[1] = 0.f; acN0[2] = 0.f; acN0[3] = 0.f;
        acN1 = acN0;
        gpart<24>(acN0, acN1, ft + ((size_t)tn * N_ + rowA) * FDIM + g4 * 8,
                  wb0p, wb1p, 128, swz, g4);
      }

      // aggregate with per-line cnt polling -> sstat
      sstat[tid] = stats_gather(stA, tid);
      __syncthreads();

      // cell0 -> h0 slot t
#pragma unroll
      for (int r = 0; r < 4; ++r) {
        int row = wbase + g4 * 4 + r;
        float2 sv0 = sstat[row * 4 + ga];
        float2 sv1 = sstat[row * 4 + ga + 2];
        float nv0 = lnrm2(accb0[r], sv0, lng0v, lnb0v);
        float nv1 = lnrm2(accb1[r], sv1, lng1v, lnb1v);
        float o0 = __shfl_xor(nv0, 8), o1 = __shfl_xor(nv1, 8);
        float vi = ga ? o0 : nv0;
        float vf = ga ? nv0 : o0;
        float vg = ga ? o1 : nv1;
        float vo = ga ? nv1 : o1;
        float igt = sigmoidf_(vi), fgt = sigmoidf_(vf), ogt = sigmoidf_(vo);
        float cn = cst[r] * fgt + igt * tanhf(vg);
        float xn = ogt * tanhf(cn) + vg;
        cst[r] = cn;
        u32 xv = f2bf(xn);
        u32 oth = __shfl_xor((int)xv, 1);
        u32 pr = (hh & 1) ? ((oth & 0xffffu) | (xv << 16)) : ((xv & 0xffffu) | (oth << 16));
        u32 p2 = __shfl_xor((int)pr, 2);
        if (ga == 0 && (hh & 3) == 0)
          st_u64g(&h0w[(size_t)row * H_ + hbase + hh], ((u64)p2 << 32) | pr);
      }
      asm volatile("s_waitcnt vmcnt(0)" ::: "memory");
      __syncthreads();
      if (tid == 0) arrive_(cnts, 1, sub);
      // fam1 wait; backpressure on fam3(t-6) via thread 8 (h0-slot reuse)
      waitfam_(cnts, 1, t1, b == 1, tid, rep,
               (t >= 7) ? 3 : -1, (t1 >= 8) ? t1 - 7 : 0);
      if ((t & 7) == fph) acqf_(tid);   // staggered: 1 fence per 8 steps
    }
  } else {
    // ================= LAYER 1 half (one step behind) ==================
    for (int t = 0; t < T_; ++t) {
      const u32 t1 = (u32)(t + 1);
      const u16* h0r = h0s + (size_t)(t & (NSLOT - 1)) * HSZ;
      u16* h1w = h1s + (size_t)(t & (NSLOT - 1)) * HSZ;
      const u16* h1r = h1s + (size_t)((t - 1) & (NSLOT - 1)) * HSZ;
      float* stA = statsB + (size_t)(t & (SSLOT - 1)) * SLSZ;

      // gemm1 part 1: A = h1(t-1) slot (own half, ready; overlaps fam1 wait)
      f32x4 ac0 = {0.f, 0.f, 0.f, 0.f}, ac1 = ac0;
      gpart<32>(ac0, ac1, h1r + (size_t)rowA * H_ + g4 * 8, wb0p, wb1p, 0, swz, g4);

      // wait for L0's h0(t); slot fresh-by-rotation, no fence needed
      if (tid == 0) pollflag_(cnts, 1, rep, t1);
      __syncthreads();
      gpart<32>(ac0, ac1, h0r + (size_t)rowA * H_ + g4 * 8, wb0p, wb1p, 128, swz, g4);
      f32x4 accb0, accb1;
#pragma unroll
      for (int r = 0; r < 4; ++r) { accb0[r] = ac0[r] + bias0v; accb1[r] = ac1[r] + bias1v; }

      // stats publish with per-line release (NO barrier)
      stats_publish(stA, accb0, accb1, wbase, g4, ga, hh, bank);

      // slack: logits+softmax(t-1) from h1(t-1) rows (L1-cached), zero slot
      if (t > 0 && wave == 0) {
        const u16* hrow = h1r + (size_t)b * H_;
        int col = lane * 16;
        bf16x8 v0 = *(const bf16x8*)(hrow + col);
        bf16x8 v1 = *(const bf16x8*)(hrow + col + 8);
        float L0v = 0.f, L1v = 0.f;
#pragma unroll
        for (int j = 0; j < 8; ++j) {
          float x0 = bf2f((u16)v0[j]);
          float2 fw = *(const float2*)&fcW[(col + j) * 2];
          L0v = fmaf(x0, fw.x, L0v); L1v = fmaf(x0, fw.y, L1v);
          float x1 = bf2f((u16)v1[j]);
          float2 fw2 = *(const float2*)&fcW[(col + 8 + j) * 2];
          L0v = fmaf(x1, fw2.x, L0v); L1v = fmaf(x1, fw2.y, L1v);
        }
#pragma unroll
        for (int off = 1; off <= 32; off <<= 1) { L0v += __shfl_xor(L0v, off); L1v += __shfl_xor(L1v, off); }
        if (lane == 0) {
          L0v += fcb0; L1v += fcb1;
          float mx = fmaxf(L0v, L1v);
          float e0 = expf(L0v - mx), e1 = expf(L1v - mx);
          float inv = 1.f / (e0 + e1);
          *(float2*)&out[((size_t)b * T_ + (t - 1)) * 2] = make_float2(e0 * inv, e1 * inv);
        }
      }
      {
        float* zs = statsB + (size_t)((t + 8) & (SSLOT - 1)) * SLSZ;
        if (tid >= 128 && tid < 256)
          st_f32g(&zs[(b * 32 + ((tid - 128) >> 2)) * 16 + (tid & 3)], 0.f);
      }

      // aggregate with per-line cnt polling -> sstat
      sstat[tid] = stats_gather(stA, tid);
      __syncthreads();

      // cell1 -> h1 slot t
#pragma unroll
      for (int r = 0; r < 4; ++r) {
        int row = wbase + g4 * 4 + r;
        float2 sv0 = sstat[row * 4 + ga];
        float2 sv1 = sstat[row * 4 + ga + 2];
        float nv0 = lnrm2(accb0[r], sv0, lng0v, lnb0v);
        float nv1 = lnrm2(accb1[r], sv1, lng1v, lnb1v);
        float o0 = __shfl_xor(nv0, 8), o1 = __shfl_xor(nv1, 8);
        float vi = ga ? o0 : nv0;
        float vf = ga ? nv0 : o0;
        float vg = ga ? o1 : nv1;
        float vo = ga ? nv1 : o1;
        float igt = sigmoidf_(vi), fgt = sigmoidf_(vf), ogt = sigmoidf_(vo);
        float cn = cst[r] * fgt + igt * tanhf(vg);
        float xn = ogt * tanhf(cn) + vg;
        cst[r] = cn;
        u32 xv = f2bf(xn);
        u32 oth = __shfl_xor((int)xv, 1);
        u32 pr = (hh & 1) ? ((oth & 0xffffu) | (xv << 16)) : ((xv & 0xffffu) | (oth << 16));
        u32 p2 = __shfl_xor((int)pr, 2);
        if (ga == 0 && (hh & 3) == 0)
          st_u64g(&h1w[(size_t)row * H_ + hbase + hh], ((u64)p2 << 32) | pr);
      }
      asm volatile("s_waitcnt vmcnt(0)" ::: "memory");
      __syncthreads();
      if (tid == 0) arrive_(cnts, 3, sub);
      waitfam_(cnts, 3, t1, b == 1, tid, rep, -1, 0);
      if ((t & 7) == fph) acqf_(tid);   // staggered: 1 fence per 8 steps
    }
    // epilogue: logits+softmax for t = T-1
    if (wave == 0) {
      const u16* hrow = h1s + (size_t)((T_ - 1) & (NSLOT - 1)) * HSZ + (size_t)b * H_;
      int col = lane * 16;
      bf16x8 v0 = *(const bf16x8*)(hrow + col);
      bf16x8 v1 = *(const bf16x8*)(hrow + col + 8);
      float L0v = 0.f, L1v = 0.f;
#pragma unroll
      for (int j = 0; j < 8; ++j) {
        float x0 = bf2f((u16)v0[j]);
        float2 fw = *(const float2*)&fcW[(col + j) * 2];
        L0v = fmaf(x0, fw.x, L0v); L1v = fmaf(x0, fw.y, L1v);
        float x1 = bf2f((u16)v1[j]);
        float2 fw2 = *(const float2*)&fcW[(col + 8 + j) * 2];
        L0v = fmaf(x1, fw2.x, L0v); L1v = fmaf(x1, fw2.y, L1v);
      }
#pragma unroll
      for (int off = 1; off <= 32; off <<= 1) { L0v += __shfl_xor(L0v, off); L1v += __shfl_xor(L1v, off); }
      if (lane == 0) {
        L0v += fcb0; L1v += fcb1;
        float mx = fmaxf(L0v, L1v);
        float e0 = expf(L0v - mx), e1 = expf(L1v - mx);
        float inv = 1.f / (e0 + e1);
        *(float2*)&out[((size_t)b * T_ + (T_ - 1)) * 2] = make_float2(e0 * inv, e1 * inv);
      }
    }
  }
}

// ---------------------------------------------------------------------------
extern "C" void kernel_launch(void* const* d_in, const int* in_sizes, int n_in,
                              void* d_out, int out_size, void* d_ws, size_t ws_size,
                              hipStream_t stream) {
  const float* x   = (const float*)d_in[0];
  const float* QnV = (const float*)d_in[1];
  const float* QlV = (const float*)d_in[2];
  const float* bng = (const float*)d_in[3];
  const float* bnb = (const float*)d_in[4];
  const float* W0  = (const float*)d_in[5];
  const float* b0  = (const float*)d_in[6];
  const float* W1  = (const float*)d_in[7];
  const float* b1  = (const float*)d_in[8];
  const float* lng = (const float*)d_in[9];
  const float* lnb = (const float*)d_in[10];
  const float* fcW = (const float*)d_in[11];
  const float* fcb = (const float*)d_in[12];
  float* out = (float*)d_out;

  // zeroed region (one memset): cnts | statsA | statsB | h0 slots | h1 slots
  u32*   cnts   = (u32*)d_ws;                            // 160*16 u32 (pad 4096)
  float* statsA = (float*)(cnts + 4096);                 // 16 slots * 256 KiB
  float* statsB = statsA + (size_t)SSLOT * SLSZ;
  u16*   h0s    = (u16*)(statsB + (size_t)SSLOT * SLSZ); // 8 * 128*1024
  u16*   h1s    = h0s + (size_t)NSLOT * HSZ;             // 8 * 128*1024
  size_t zero_bytes = (size_t)((char*)(h1s + (size_t)NSLOT * HSZ) - (char*)d_ws);

  float* scale = (float*)(h1s + (size_t)NSLOT * HSZ);    // 64
  float* shift = scale + 64;                             // 64
  u16* ft   = (u16*)(shift + 64);                        // 256*128*768
  u16* WtP0 = ft + (size_t)N_ * T_ * FDIM;               // 4096*1792
  u16* WtP1 = WtP0 + (size_t)G4 * K0_;                   // 4096*2048

  hipMemsetAsync(d_ws, 0, zero_bytes, stream);

  bn_stats_k<<<QN_, 256, 0, stream>>>(x, bng, bnb, scale, shift);
  feats_all_k<<<N_ * T_, 256, 0, stream>>>(x, scale, shift, QnV, QlV, ft);
  wconv_k<<<dim3(K0_ / 64, G4 / 64), 256, 0, stream>>>(W0, WtP0, K0_);
  wconv_k<<<dim3(K1_ / 64, G4 / 64), 256, 0, stream>>>(W1, WtP1, K1_);

  void* args[] = {
    (void*)&WtP0, (void*)&WtP1, (void*)&ft, (void*)&h0s, (void*)&h1s,
    (void*)&b0, (void*)&b1, (void*)&lng, (void*)&lnb,
    (void*)&fcW, (void*)&fcb, (void*)&statsA, (void*)&statsB,
    (void*)&cnts, (void*)&out
  };
  hipLaunchCooperativeKernel((void*)persist_k, dim3(256), dim3(512), args, 0, stream);
}

// Round 15
// 8310.099 us; speedup vs baseline: 1.6181x; 1.6181x over previous
//
#include <hip/hip_runtime.h>
#include <math.h>

// ---------------------------------------------------------------------------
// LSTMModel round 15: REVERT to R13 (best measured: 8.31 ms). R14's
// self-validating stats lines caused a per-line poll storm (128 pollers x
// 4096 sc1 lines + doubled RMW count): 13.4 ms, FETCH/WRITE +50%.
// R13 = layer-pipelined persistent kernel with: closer barriers + replicated
// flags, 8-way banked stats atomicAdd + CACHED aggregation, depth-8 h slot
// rotation (fence-free steady state, staggered 1 acq-fence/8 steps),
// sc1 write-through h stores, slack-hidden ft-gemm/zeroing/logits.
// Blocks 0..127 = layer 0 (step t), 128..255 = layer 1 (one step behind).
// ---------------------------------------------------------------------------

#define N_   128
#define T_   256
#define QN_  16
#define INX  24
#define H_   1024
#define G4   4096
#define FDIM 768
#define EPS_ 1e-5f
#define K0_  1792
#define K1_  2048
#define NSLOT 8
#define HSZ  ((size_t)N_ * H_)
#define SSLOT 16
#define SLSZ (512 * 8 * 16)      // floats per stats slot: 512 entries x 8 banks x 16

typedef unsigned short u16;
typedef unsigned int u32;
typedef unsigned long long u64;
typedef __attribute__((ext_vector_type(8))) short bf16x8;
typedef __attribute__((ext_vector_type(4))) float f32x4;

__device__ __forceinline__ float sigmoidf_(float v) { return 1.0f / (1.0f + expf(-v)); }

__device__ __forceinline__ u16 f2bf(float f) {
  unsigned u = __float_as_uint(f);
  u += 0x7fffu + ((u >> 16) & 1u);
  return (u16)(u >> 16);
}
__device__ __forceinline__ float bf2f(u16 x) {
  return __uint_as_float((u32)x << 16);
}

__device__ __forceinline__ void st_u64g(void* p, u64 v) {
  __hip_atomic_store((u64*)p, v, __ATOMIC_RELAXED, __HIP_MEMORY_SCOPE_AGENT);
}
__device__ __forceinline__ void st_f32g(float* p, float v) {
  __hip_atomic_store(p, v, __ATOMIC_RELAXED, __HIP_MEMORY_SCOPE_AGENT);
}
__device__ __forceinline__ void atomAdd_(float* p, float v) {
  __hip_atomic_fetch_add(p, v, __ATOMIC_RELAXED, __HIP_MEMORY_SCOPE_AGENT);
}

// ---- BatchNorm stats over the (N*T, 16) numeric block --------------------
__global__ __launch_bounds__(256) void bn_stats_k(const float* __restrict__ x,
    const float* __restrict__ gamma, const float* __restrict__ beta,
    float* __restrict__ scale, float* __restrict__ shift) {
  int q = blockIdx.x;
  int tid = threadIdx.x;
  float s = 0.f, s2 = 0.f;
  for (int r = tid; r < N_ * T_; r += 256) {
    float v = x[(size_t)r * INX + q];
    s += v; s2 += v * v;
  }
  for (int off = 32; off; off >>= 1) { s += __shfl_down(s, off); s2 += __shfl_down(s2, off); }
  __shared__ float red[2][4];
  int w = tid >> 6;
  if ((tid & 63) == 0) { red[0][w] = s; red[1][w] = s2; }
  __syncthreads();
  if (tid == 0) {
    float S = 0.f, S2 = 0.f;
    for (int i = 0; i < 4; ++i) { S += red[0][i]; S2 += red[1][i]; }
    float m   = S  / (float)(N_ * T_);
    float var = S2 / (float)(N_ * T_) - m * m;
    float rs  = rsqrtf(var + EPS_);
    scale[q] = rs * gamma[q];
    shift[q] = beta[q] - m * rs * gamma[q];
  }
}

// ---- Feature build for ALL steps: ft[t][n][768] bf16 ---------------------
__global__ __launch_bounds__(256) void feats_all_k(const float* __restrict__ x,
    const float* __restrict__ scale, const float* __restrict__ shift,
    const float* __restrict__ QnV, const float* __restrict__ QlV,
    u16* __restrict__ ft) {
  int rid = blockIdx.x;              // t*128 + n
  int t = rid >> 7, n = rid & 127;
  const float* xr = x + ((size_t)n * T_ + t) * INX;
  u16* frow = ft + (size_t)rid * FDIM;
  for (int f = threadIdx.x; f < FDIM; f += 256) {
    int d = f & 31;
    float v;
    if (f < 512) {
      int q = f >> 5;
      v = (xr[q] * scale[q] + shift[q]) * QnV[q * 32 + d];
    } else {
      int cg_ = (f - 512) >> 5;
      int idx = (int)xr[QN_ + cg_] + cg_ * 100;
      v = QlV[idx * 32 + d];
    }
    frow[f] = f2bf(v);
  }
}

// ---- Weight convert: W[k][col] fp32 -> WtP[(b*32+j)][k] bf16 --------------
__global__ __launch_bounds__(256) void wconv_k(const float* __restrict__ W,
                                               u16* __restrict__ WtP, int K) {
  __shared__ u16 L[64][72];
  int tid = threadIdx.x;
  int k0 = blockIdx.x * 64, n0 = blockIdx.y * 64;
#pragma unroll
  for (int it = 0; it < 16; ++it) {
    int e = it * 256 + tid;
    int r = e >> 6, c = e & 63;
    L[r][c] = f2bf(W[(size_t)(k0 + r) * G4 + n0 + c]);
  }
  __syncthreads();
  int n = tid >> 2, ks = (tid & 3) << 4;
  int col = n0 + n;
  int b = (col & 1023) >> 3;
  int j = (col >> 10) * 8 + (col & 7);
  u16* dst = WtP + ((size_t)(b * 32 + j)) * K + k0 + ks;
#pragma unroll
  for (int jj = 0; jj < 16; ++jj) dst[jj] = L[ks + jj][n];
}

// ---- closer barrier with replicated flags --------------------------------
// layout (64B lines): [0..31] arrival subs (fam*8+sub), [32..159] flag
// replicas fam*32+rep, all padded *16 u32.
#define SUBC(fam, sub)  cnts[((fam) * 8 + (sub)) * 16]
#define FLAGR(fam, rep) cnts[(32 + (fam) * 32 + (rep)) * 16]

__device__ __forceinline__ void arrive_(u32* cnts, int fam, int sub) {
  __hip_atomic_fetch_add(&SUBC(fam, sub), 1u,
                         __ATOMIC_RELAXED, __HIP_MEMORY_SCOPE_AGENT);
}
__device__ __forceinline__ void pollsub_(u32* cnts, int fam, int sub, u32 tgt16) {
  while (__hip_atomic_load(&SUBC(fam, sub), __ATOMIC_RELAXED, __HIP_MEMORY_SCOPE_AGENT) < tgt16)
    __builtin_amdgcn_s_sleep(1);
}
__device__ __forceinline__ void pollflag_(u32* cnts, int fam, int rep, u32 t1) {
  while (__hip_atomic_load(&FLAGR(fam, rep), __ATOMIC_RELAXED, __HIP_MEMORY_SCOPE_AGENT) < t1)
    __builtin_amdgcn_s_sleep(1);
}
__device__ __forceinline__ void acqf_(int tid) {
  if (tid < 64) __builtin_amdgcn_fence(__ATOMIC_ACQUIRE, "agent");  // buffer_inv only
  __syncthreads();
}

// wait for family barrier. closer block: 8 threads poll the arrival subs,
// then 32 threads store the 32 flag replicas. other blocks: 1 thread polls
// own replica. thread 8 concurrently does optional backpressure poll.
__device__ __forceinline__ void waitfam_(u32* cnts, int fam, u32 t1, int isCloser,
                                         int tid, int rep, int bpFam, u32 bpT1) {
  if (isCloser) { if (tid < 8) pollsub_(cnts, fam, tid, t1 * 16u); }
  else          { if (tid == 0) pollflag_(cnts, fam, rep, t1); }
  if (tid == 8 && bpFam >= 0) pollflag_(cnts, bpFam, rep, bpT1);
  __syncthreads();
  if (isCloser && tid < 32)
    __hip_atomic_store(&FLAGR(fam, tid), t1, __ATOMIC_RELAXED, __HIP_MEMORY_SCOPE_AGENT);
}

// ---- K-partial MFMA over NS slices of 32 (cached A loads) ----------------
template<int NS>
__device__ __forceinline__ void gpart(f32x4& a0, f32x4& a1,
    const u16* __restrict__ abase, const u16* __restrict__ wb0,
    const u16* __restrict__ wb1, int cb, int swz, int g) {
#pragma unroll 8
  for (int kc = 0; kc < NS; ++kc) {
    bf16x8 av = *(const bf16x8*)(abase + kc * 32);
    int c = ((cb + kc * 4 + g) ^ swz) << 3;
    bf16x8 bv0 = *(const bf16x8*)(wb0 + c);
    bf16x8 bv1 = *(const bf16x8*)(wb1 + c);
    a0 = __builtin_amdgcn_mfma_f32_16x16x32_bf16(av, bv0, a0, 0, 0, 0);
    a1 = __builtin_amdgcn_mfma_f32_16x16x32_bf16(av, bv1, a1, 0, 0, 0);
  }
}

__device__ __forceinline__ float lnrm2(float v, float2 sq, float g_, float b_) {
  float mean = sq.x * (1.f / (float)H_);
  float var  = sq.y * (1.f / (float)H_) - mean * mean;
  return (v - mean) * rsqrtf(var + EPS_) * g_ + b_;
}

// ---- The layer-pipelined persistent kernel --------------------------------
__global__ __launch_bounds__(512, 2) void persist_k(
    const u16* __restrict__ WtP0, const u16* __restrict__ WtP1,
    const u16* __restrict__ ft,
    u16* __restrict__ h0s, u16* __restrict__ h1s,
    const float* __restrict__ b0, const float* __restrict__ b1,
    const float* __restrict__ lng, const float* __restrict__ lnb,
    const float* __restrict__ fcW, const float* __restrict__ fcb,
    float* __restrict__ statsA, float* __restrict__ statsB,
    u32* __restrict__ cnts, float* __restrict__ out) {
  __shared__ u16 wlds[32 * K1_];               // 128 KiB (L0 uses 112 KiB)
  __shared__ float2 sstat[512];                // aggregated LN stats (4 KiB)
  const int bcu = blockIdx.x, tid = threadIdx.x;
  const int isL0 = bcu < 128;
  const int b    = isL0 ? bcu : bcu - 128;
  const int wave = tid >> 6, lane = tid & 63;
  const int vcol = lane & 15, g4 = lane >> 4;
  const int ga = vcol >> 3, hh = vcol & 7;
  const int swz = vcol & 7;
  const int rowA  = wave * 16 + vcol;
  const int wbase = wave * 16;
  const int sub   = b >> 4;
  const int bank  = b & 7;
  const int rep   = b & 31;
  const int fph   = b & 7;        // staggered fence phase
  const int hbase = b * 8;
  const int K = isL0 ? K0_ : K1_;

  // ---- one-time: weight slice global -> LDS (XOR chunk swizzle) ----
  {
    const u16* wsrc = isL0 ? WtP0 + (size_t)b * 32 * K0_
                           : WtP1 + (size_t)b * 32 * K1_;
    int kc8 = K >> 3;
    for (int cid = tid; cid < 32 * kc8; cid += 512) {
      int j = cid / kc8, ck = cid - j * kc8;
      *(bf16x8*)&wlds[j * K + ((ck ^ (j & 7)) << 3)] =
          *(const bf16x8*)&wsrc[(size_t)j * K + (ck << 3)];
    }
  }
  __syncthreads();
  acqf_(tid);   // clean any cross-replay stale lines once

  const u16* wb0p = &wlds[vcol * K];
  const u16* wb1p = &wlds[(vcol + 16) * K];

  const float* bW   = isL0 ? b0 : b1;
  const float* lngW = isL0 ? lng : lng + 4 * H_;
  const float* lnbW = isL0 ? lnb : lnb + 4 * H_;
  const int colA = ga * H_ + hbase + hh;
  const int colB = (ga + 2) * H_ + hbase + hh;
  const float bias0v = bW[colA], bias1v = bW[colB];
  const float lng0v = lngW[colA], lnb0v = lnbW[colA];
  const float lng1v = lngW[colB], lnb1v = lnbW[colB];
  const float fcb0 = fcb[0], fcb1 = fcb[1];

  float cst[4] = {0.f, 0.f, 0.f, 0.f};

  if (isL0) {
    // ================= LAYER 0 half ====================================
    f32x4 acN0 = {0.f, 0.f, 0.f, 0.f}, acN1 = acN0;
    gpart<24>(acN0, acN1, ft + (size_t)rowA * FDIM + g4 * 8, wb0p, wb1p, 128, swz, g4);

    for (int t = 0; t < T_; ++t) {
      const u32 t1 = (u32)(t + 1);
      u16* h0w = h0s + (size_t)(t & (NSLOT - 1)) * HSZ;
      const u16* h0r = h0s + (size_t)((t - 1) & (NSLOT - 1)) * HSZ;
      float* stA = statsA + (size_t)(t & (SSLOT - 1)) * SLSZ;

      // gemm0 h-part: cached reads of h0(t-1) slot (never-stale by rotation)
      f32x4 ac0 = acN0, ac1 = acN1;
      gpart<32>(ac0, ac1, h0r + (size_t)rowA * H_ + g4 * 8, wb0p, wb1p, 0, swz, g4);
      f32x4 accb0, accb1;
#pragma unroll
      for (int r = 0; r < 4; ++r) { accb0[r] = ac0[r] + bias0v; accb1[r] = ac1[r] + bias1v; }

      // stats publish: banked lines, 32 RMW/line
#pragma unroll
      for (int r = 0; r < 4; ++r) {
        int row = wbase + g4 * 4 + r;
        float s0 = accb0[r], q0 = s0 * s0, s1 = accb1[r], q1 = s1 * s1;
#pragma unroll
        for (int off = 1; off <= 4; off <<= 1) {
          s0 += __shfl_xor(s0, off); q0 += __shfl_xor(q0, off);
          s1 += __shfl_xor(s1, off); q1 += __shfl_xor(q1, off);
        }
        if (hh == 0) {
          float* l0 = &stA[(((row * 4 + ga) * 8) + bank) * 16];
          float* l1 = &stA[(((row * 4 + ga + 2) * 8) + bank) * 16];
          atomAdd_(l0, s0);     atomAdd_(l0 + 1, q0);
          atomAdd_(l1, s1);     atomAdd_(l1 + 1, q1);
        }
      }
      asm volatile("s_waitcnt vmcnt(0)" ::: "memory");
      __syncthreads();
      if (tid == 0) arrive_(cnts, 0, sub);

      // slack: zero stats slot t+8 (own 32 lines), prefetch ft-part for t+1
      {
        float* zs = statsA + (size_t)((t + 8) & (SSLOT - 1)) * SLSZ;
        if (tid < 64) st_f32g(&zs[(b * 32 + (tid >> 1)) * 16 + (tid & 1)], 0.f);
        int tn = (t + 1 < T_) ? t + 1 : t;
        acN0[0] = 0.f; acN0[1] = 0.f; acN0[2] = 0.f; acN0[3] = 0.f;
        acN1 = acN0;
        gpart<24>(acN0, acN1, ft + ((size_t)tn * N_ + rowA) * FDIM + g4 * 8,
                  wb0p, wb1p, 128, swz, g4);
      }
      // wait fam0 (closer: b==0); backpressure on fam2 via thread 8
      waitfam_(cnts, 0, t1, b == 0, tid, rep,
               (t >= 7) ? 2 : -1, (u32)(t - 6));

      // aggregate 8 banks -> sstat (CACHED reads; fresh by rotation+fence)
      {
        const float* lp = &stA[(size_t)tid * 128];
        float s = 0.f, q = 0.f;
#pragma unroll
        for (int k = 0; k < 8; ++k) {
          float2 v = *(const float2*)(lp + k * 16);
          s += v.x; q += v.y;
        }
        sstat[tid] = make_float2(s, q);
      }
      __syncthreads();

      // cell0 -> h0 slot t
#pragma unroll
      for (int r = 0; r < 4; ++r) {
        int row = wbase + g4 * 4 + r;
        float2 sv0 = sstat[row * 4 + ga];
        float2 sv1 = sstat[row * 4 + ga + 2];
        float nv0 = lnrm2(accb0[r], sv0, lng0v, lnb0v);
        float nv1 = lnrm2(accb1[r], sv1, lng1v, lnb1v);
        float o0 = __shfl_xor(nv0, 8), o1 = __shfl_xor(nv1, 8);
        float vi = ga ? o0 : nv0;
        float vf = ga ? nv0 : o0;
        float vg = ga ? o1 : nv1;
        float vo = ga ? nv1 : o1;
        float igt = sigmoidf_(vi), fgt = sigmoidf_(vf), ogt = sigmoidf_(vo);
        float cn = cst[r] * fgt + igt * tanhf(vg);
        float xn = ogt * tanhf(cn) + vg;
        cst[r] = cn;
        u32 xv = f2bf(xn);
        u32 oth = __shfl_xor((int)xv, 1);
        u32 pr = (hh & 1) ? ((oth & 0xffffu) | (xv << 16)) : ((xv & 0xffffu) | (oth << 16));
        u32 p2 = __shfl_xor((int)pr, 2);
        if (ga == 0 && (hh & 3) == 0)
          st_u64g(&h0w[(size_t)row * H_ + hbase + hh], ((u64)p2 << 32) | pr);
      }
      asm volatile("s_waitcnt vmcnt(0)" ::: "memory");
      __syncthreads();
      if (tid == 0) arrive_(cnts, 1, sub);
      waitfam_(cnts, 1, t1, b == 1, tid, rep, -1, 0);
      if ((t & 7) == fph) acqf_(tid);   // staggered: 1 fence per 8 steps
    }
  } else {
    // ================= LAYER 1 half (one step behind) ==================
    for (int t = 0; t < T_; ++t) {
      const u32 t1 = (u32)(t + 1);
      const u16* h0r = h0s + (size_t)(t & (NSLOT - 1)) * HSZ;
      u16* h1w = h1s + (size_t)(t & (NSLOT - 1)) * HSZ;
      const u16* h1r = h1s + (size_t)((t - 1) & (NSLOT - 1)) * HSZ;
      float* stA = statsB + (size_t)(t & (SSLOT - 1)) * SLSZ;

      // gemm1 part 1: A = h1(t-1) slot (own half, ready; overlaps fam1 wait)
      f32x4 ac0 = {0.f, 0.f, 0.f, 0.f}, ac1 = ac0;
      gpart<32>(ac0, ac1, h1r + (size_t)rowA * H_ + g4 * 8, wb0p, wb1p, 0, swz, g4);

      // wait for L0's h0(t); slot fresh-by-rotation, no fence needed
      if (tid == 0) pollflag_(cnts, 1, rep, t1);
      __syncthreads();
      gpart<32>(ac0, ac1, h0r + (size_t)rowA * H_ + g4 * 8, wb0p, wb1p, 128, swz, g4);
      f32x4 accb0, accb1;
#pragma unroll
      for (int r = 0; r < 4; ++r) { accb0[r] = ac0[r] + bias0v; accb1[r] = ac1[r] + bias1v; }

      // stats publish (banked lines)
#pragma unroll
      for (int r = 0; r < 4; ++r) {
        int row = wbase + g4 * 4 + r;
        float s0 = accb0[r], q0 = s0 * s0, s1 = accb1[r], q1 = s1 * s1;
#pragma unroll
        for (int off = 1; off <= 4; off <<= 1) {
          s0 += __shfl_xor(s0, off); q0 += __shfl_xor(q0, off);
          s1 += __shfl_xor(s1, off); q1 += __shfl_xor(q1, off);
        }
        if (hh == 0) {
          float* l0 = &stA[(((row * 4 + ga) * 8) + bank) * 16];
          float* l1 = &stA[(((row * 4 + ga + 2) * 8) + bank) * 16];
          atomAdd_(l0, s0);     atomAdd_(l0 + 1, q0);
          atomAdd_(l1, s1);     atomAdd_(l1 + 1, q1);
        }
      }
      asm volatile("s_waitcnt vmcnt(0)" ::: "memory");
      __syncthreads();
      if (tid == 0) arrive_(cnts, 2, sub);

      // slack: logits+softmax(t-1) from h1(t-1) rows (L1-cached), zero slot
      if (t > 0 && wave == 0) {
        const u16* hrow = h1r + (size_t)b * H_;
        int col = lane * 16;
        bf16x8 v0 = *(const bf16x8*)(hrow + col);
        bf16x8 v1 = *(const bf16x8*)(hrow + col + 8);
        float L0v = 0.f, L1v = 0.f;
#pragma unroll
        for (int j = 0; j < 8; ++j) {
          float x0 = bf2f((u16)v0[j]);
          float2 fw = *(const float2*)&fcW[(col + j) * 2];
          L0v = fmaf(x0, fw.x, L0v); L1v = fmaf(x0, fw.y, L1v);
          float x1 = bf2f((u16)v1[j]);
          float2 fw2 = *(const float2*)&fcW[(col + 8 + j) * 2];
          L0v = fmaf(x1, fw2.x, L0v); L1v = fmaf(x1, fw2.y, L1v);
        }
#pragma unroll
        for (int off = 1; off <= 32; off <<= 1) { L0v += __shfl_xor(L0v, off); L1v += __shfl_xor(L1v, off); }
        if (lane == 0) {
          L0v += fcb0; L1v += fcb1;
          float mx = fmaxf(L0v, L1v);
          float e0 = expf(L0v - mx), e1 = expf(L1v - mx);
          float inv = 1.f / (e0 + e1);
          *(float2*)&out[((size_t)b * T_ + (t - 1)) * 2] = make_float2(e0 * inv, e1 * inv);
        }
      }
      {
        float* zs = statsB + (size_t)((t + 8) & (SSLOT - 1)) * SLSZ;
        if (tid >= 64 && tid < 128)
          st_f32g(&zs[(b * 32 + ((tid - 64) >> 1)) * 16 + (tid & 1)], 0.f);
      }
      // wait fam2 (closer: b==0)
      waitfam_(cnts, 2, t1, b == 0, tid, rep, -1, 0);

      // aggregate 8 banks -> sstat (CACHED reads)
      {
        const float* lp = &stA[(size_t)tid * 128];
        float s = 0.f, q = 0.f;
#pragma unroll
        for (int k = 0; k < 8; ++k) {
          float2 v = *(const float2*)(lp + k * 16);
          s += v.x; q += v.y;
        }
        sstat[tid] = make_float2(s, q);
      }
      __syncthreads();

      // cell1 -> h1 slot t
#pragma unroll
      for (int r = 0; r < 4; ++r) {
        int row = wbase + g4 * 4 + r;
        float2 sv0 = sstat[row * 4 + ga];
        float2 sv1 = sstat[row * 4 + ga + 2];
        float nv0 = lnrm2(accb0[r], sv0, lng0v, lnb0v);
        float nv1 = lnrm2(accb1[r], sv1, lng1v, lnb1v);
        float o0 = __shfl_xor(nv0, 8), o1 = __shfl_xor(nv1, 8);
        float vi = ga ? o0 : nv0;
        float vf = ga ? nv0 : o0;
        float vg = ga ? o1 : nv1;
        float vo = ga ? nv1 : o1;
        float igt = sigmoidf_(vi), fgt = sigmoidf_(vf), ogt = sigmoidf_(vo);
        float cn = cst[r] * fgt + igt * tanhf(vg);
        float xn = ogt * tanhf(cn) + vg;
        cst[r] = cn;
        u32 xv = f2bf(xn);
        u32 oth = __shfl_xor((int)xv, 1);
        u32 pr = (hh & 1) ? ((oth & 0xffffu) | (xv << 16)) : ((xv & 0xffffu) | (oth << 16));
        u32 p2 = __shfl_xor((int)pr, 2);
        if (ga == 0 && (hh & 3) == 0)
          st_u64g(&h1w[(size_t)row * H_ + hbase + hh], ((u64)p2 << 32) | pr);
      }
      asm volatile("s_waitcnt vmcnt(0)" ::: "memory");
      __syncthreads();
      if (tid == 0) arrive_(cnts, 3, sub);
      waitfam_(cnts, 3, t1, b == 1, tid, rep, -1, 0);
      if ((t & 7) == fph) acqf_(tid);   // staggered: 1 fence per 8 steps
    }
    // epilogue: logits+softmax for t = T-1
    if (wave == 0) {
      const u16* hrow = h1s + (size_t)((T_ - 1) & (NSLOT - 1)) * HSZ + (size_t)b * H_;
      int col = lane * 16;
      bf16x8 v0 = *(const bf16x8*)(hrow + col);
      bf16x8 v1 = *(const bf16x8*)(hrow + col + 8);
      float L0v = 0.f, L1v = 0.f;
#pragma unroll
      for (int j = 0; j < 8; ++j) {
        float x0 = bf2f((u16)v0[j]);
        float2 fw = *(const float2*)&fcW[(col + j) * 2];
        L0v = fmaf(x0, fw.x, L0v); L1v = fmaf(x0, fw.y, L1v);
        float x1 = bf2f((u16)v1[j]);
        float2 fw2 = *(const float2*)&fcW[(col + 8 + j) * 2];
        L0v = fmaf(x1, fw2.x, L0v); L1v = fmaf(x1, fw2.y, L1v);
      }
#pragma unroll
      for (int off = 1; off <= 32; off <<= 1) { L0v += __shfl_xor(L0v, off); L1v += __shfl_xor(L1v, off); }
      if (lane == 0) {
        L0v += fcb0; L1v += fcb1;
        float mx = fmaxf(L0v, L1v);
        float e0 = expf(L0v - mx), e1 = expf(L1v - mx);
        float inv = 1.f / (e0 + e1);
        *(float2*)&out[((size_t)b * T_ + (T_ - 1)) * 2] = make_float2(e0 * inv, e1 * inv);
      }
    }
  }
}

// ---------------------------------------------------------------------------
extern "C" void kernel_launch(void* const* d_in, const int* in_sizes, int n_in,
                              void* d_out, int out_size, void* d_ws, size_t ws_size,
                              hipStream_t stream) {
  const float* x   = (const float*)d_in[0];
  const float* QnV = (const float*)d_in[1];
  const float* QlV = (const float*)d_in[2];
  const float* bng = (const float*)d_in[3];
  const float* bnb = (const float*)d_in[4];
  const float* W0  = (const float*)d_in[5];
  const float* b0  = (const float*)d_in[6];
  const float* W1  = (const float*)d_in[7];
  const float* b1  = (const float*)d_in[8];
  const float* lng = (const float*)d_in[9];
  const float* lnb = (const float*)d_in[10];
  const float* fcW = (const float*)d_in[11];
  const float* fcb = (const float*)d_in[12];
  float* out = (float*)d_out;

  // zeroed region (one memset): cnts | statsA | statsB | h0 slots | h1 slots
  u32*   cnts   = (u32*)d_ws;                            // 160*16 u32 (pad 4096)
  float* statsA = (float*)(cnts + 4096);                 // 16 slots * 256 KiB
  float* statsB = statsA + (size_t)SSLOT * SLSZ;
  u16*   h0s    = (u16*)(statsB + (size_t)SSLOT * SLSZ); // 8 * 128*1024
  u16*   h1s    = h0s + (size_t)NSLOT * HSZ;             // 8 * 128*1024
  size_t zero_bytes = (size_t)((char*)(h1s + (size_t)NSLOT * HSZ) - (char*)d_ws);

  float* scale = (float*)(h1s + (size_t)NSLOT * HSZ);    // 64
  float* shift = scale + 64;                             // 64
  u16* ft   = (u16*)(shift + 64);                        // 256*128*768
  u16* WtP0 = ft + (size_t)N_ * T_ * FDIM;               // 4096*1792
  u16* WtP1 = WtP0 + (size_t)G4 * K0_;                   // 4096*2048

  hipMemsetAsync(d_ws, 0, zero_bytes, stream);

  bn_stats_k<<<QN_, 256, 0, stream>>>(x, bng, bnb, scale, shift);
  feats_all_k<<<N_ * T_, 256, 0, stream>>>(x, scale, shift, QnV, QlV, ft);
  wconv_k<<<dim3(K0_ / 64, G4 / 64), 256, 0, stream>>>(W0, WtP0, K0_);
  wconv_k<<<dim3(K1_ / 64, G4 / 64), 256, 0, stream>>>(W1, WtP1, K1_);

  void* args[] = {
    (void*)&WtP0, (void*)&WtP1, (void*)&ft, (void*)&h0s, (void*)&h1s,
    (void*)&b0, (void*)&b1, (void*)&lng, (void*)&lnb,
    (void*)&fcW, (void*)&fcb, (void*)&statsA, (void*)&statsB,
    (void*)&cnts, (void*)&out
  };
  hipLaunchCooperativeKernel((void*)persist_k, dim3(256), dim3(512), args, 0, stream);
}